// Round 1
// baseline (75117.273 us; speedup 1.0000x reference)
//
#include <hip/hip_runtime.h>

#define NQ 4096
#define NM 8192
#define DK 128
#define DV 512
#define BATCH 2

constexpr float P_SCALAR = 40.0f;
constexpr float NEG_INF = -1e9f;

// ---------------------------------------------------------------------------
// Kernel 0: per-batch any(qmask), any(mmask)
// ---------------------------------------------------------------------------
__global__ void flags_kernel(const int* __restrict__ qmask,
                             const int* __restrict__ mmask,
                             int* __restrict__ flags) {
    const int b = blockIdx.x;
    __shared__ int aq, am;
    if (threadIdx.x == 0) { aq = 0; am = 0; }
    __syncthreads();
    int lq = 0, lm = 0;
    for (int i = threadIdx.x; i < NQ; i += blockDim.x) lq |= (qmask[b * NQ + i] != 0);
    for (int i = threadIdx.x; i < NM; i += blockDim.x) lm |= (mmask[b * NM + i] != 0);
    if (lq) atomicOr(&aq, 1);
    if (lm) atomicOr(&am, 1);
    __syncthreads();
    if (threadIdx.x == 0) {
        flags[b * 2 + 0] = aq;
        flags[b * 2 + 1] = am;
    }
}

// ---------------------------------------------------------------------------
// Kernel 1: per-query-column online softmax stats (max, sum-exp) over memory.
// q-tile = 32, m-tile = 64, block = 256 (16 i-groups x 16 j-groups, 4x2 regs)
// ---------------------------------------------------------------------------
__global__ __launch_bounds__(256) void pass1_kernel(
    const float* __restrict__ qkey, const float* __restrict__ mkey,
    const int* __restrict__ mmask,
    float* __restrict__ colmax, float* __restrict__ colsum) {
    const int b = blockIdx.y;
    const int qbase = blockIdx.x * 32;
    const int t = threadIdx.x;
    const int ti = t & 15;   // i = ti*4 + u
    const int tj = t >> 4;   // j = tj*2 + v

    __shared__ float Qs[DK][32];
    __shared__ float Ks[DK][64];
    __shared__ float red[32][17];
    __shared__ float tmax[32];
    __shared__ float mstat[32];
    __shared__ float lstat[32];

    const float* qp = qkey + (size_t)b * DK * NQ + qbase;
    for (int l = t; l < DK * 32; l += 256) {
        int d = l >> 5, j = l & 31;
        Qs[d][j] = qp[(size_t)d * NQ + j];
    }
    if (t < 32) { mstat[t] = -3.0e38f; lstat[t] = 0.0f; }
    __syncthreads();

    const float* kp = mkey + (size_t)b * DK * NM;
    const int* mmp = mmask + b * NM;

    for (int mbase = 0; mbase < NM; mbase += 64) {
        for (int l = t; l < DK * 64; l += 256) {
            int d = l >> 6, i = l & 63;
            Ks[d][i] = kp[(size_t)d * NM + mbase + i];
        }
        __syncthreads();

        float acc[4][2] = {};
        for (int d = 0; d < DK; ++d) {
            float4 kv = *(const float4*)&Ks[d][ti * 4];
            float2 qv = *(const float2*)&Qs[d][tj * 2];
            acc[0][0] += kv.x * qv.x; acc[0][1] += kv.x * qv.y;
            acc[1][0] += kv.y * qv.x; acc[1][1] += kv.y * qv.y;
            acc[2][0] += kv.z * qv.x; acc[2][1] += kv.z * qv.y;
            acc[3][0] += kv.w * qv.x; acc[3][1] += kv.w * qv.y;
        }

        float s[4][2];
#pragma unroll
        for (int u = 0; u < 4; ++u) {
            int mmv = mmp[mbase + ti * 4 + u];
#pragma unroll
            for (int v = 0; v < 2; ++v)
                s[u][v] = mmv ? acc[u][v] * P_SCALAR : NEG_INF;
        }
#pragma unroll
        for (int v = 0; v < 2; ++v) {
            float lm = fmaxf(fmaxf(s[0][v], s[1][v]), fmaxf(s[2][v], s[3][v]));
            red[tj * 2 + v][ti] = lm;
        }
        __syncthreads();
        if (t < 32) {
            float m = red[t][0];
            for (int k = 1; k < 16; ++k) m = fmaxf(m, red[t][k]);
            tmax[t] = m;
        }
        __syncthreads();
#pragma unroll
        for (int v = 0; v < 2; ++v) {
            float tm = tmax[tj * 2 + v];
            float ps = 0.f;
#pragma unroll
            for (int u = 0; u < 4; ++u) ps += __expf(s[u][v] - tm);
            red[tj * 2 + v][ti] = ps;
        }
        __syncthreads();
        if (t < 32) {
            float ts = 0.f;
            for (int k = 0; k < 16; ++k) ts += red[t][k];
            float tm = tmax[t];
            float mo = mstat[t];
            float mn = fmaxf(mo, tm);
            lstat[t] = lstat[t] * __expf(mo - mn) + ts * __expf(tm - mn);
            mstat[t] = mn;
        }
        __syncthreads();
    }
    if (t < 32) {
        colmax[b * NQ + qbase + t] = mstat[t];
        colsum[b * NQ + qbase + t] = lstat[t];
    }
}

// ---------------------------------------------------------------------------
// Kernel 2: recompute S, P = exp(s-max)/sum, accumulate O = V*P, write out.
// q-tile = 16, m-tile = 64, Dv chunked 4x128. block = 256.
// ---------------------------------------------------------------------------
__global__ __launch_bounds__(256) void pass2_kernel(
    const float* __restrict__ qkey, const float* __restrict__ mkey,
    const float* __restrict__ mval,
    const int* __restrict__ qmask, const int* __restrict__ mmask,
    const int* __restrict__ flags,
    const float* __restrict__ colmax, const float* __restrict__ colsum,
    float* __restrict__ out) {
    const int b = blockIdx.y;
    const int qbase = blockIdx.x * 16;
    const int t = threadIdx.x;

    __shared__ float Qs[DK][16];
    __shared__ float Ks[DK][64];
    __shared__ float Ps[64][17];    // [i][j]
    __shared__ float Vs[64][132];   // [i][dv_row in chunk], padded
    __shared__ float cm[16], rs[16];

    const float* qp = qkey + (size_t)b * DK * NQ + qbase;
    for (int l = t; l < DK * 16; l += 256) {
        int d = l >> 4, j = l & 15;
        Qs[d][j] = qp[(size_t)d * NQ + j];
    }
    if (t < 16) {
        cm[t] = colmax[b * NQ + qbase + t];
        rs[t] = 1.0f / colsum[b * NQ + qbase + t];
    }

    const int si = t & 63;    // S phase: i
    const int sjg = t >> 6;   // S phase: j group of 4
    const int aj = t & 15;    // accumulate: j
    const int adv = t >> 4;   // accumulate: dv sub-row group (8 rows)

    float O[32];
#pragma unroll
    for (int k = 0; k < 32; ++k) O[k] = 0.f;

    const float* kp = mkey + (size_t)b * DK * NM;
    const float* vp = mval + (size_t)b * DV * NM;
    const int* mmp = mmask + b * NM;

    __syncthreads();

    for (int mbase = 0; mbase < NM; mbase += 64) {
        // stage K tile (128 x 64)
        for (int l = t; l < DK * 64; l += 256) {
            int d = l >> 6, i = l & 63;
            Ks[d][i] = kp[(size_t)d * NM + mbase + i];
        }
        __syncthreads();

        // S (64 x 16) -> P
        float acc[4] = {0.f, 0.f, 0.f, 0.f};
        for (int d = 0; d < DK; ++d) {
            float kv = Ks[d][si];
            float4 qv = *(const float4*)&Qs[d][sjg * 4];
            acc[0] += kv * qv.x; acc[1] += kv * qv.y;
            acc[2] += kv * qv.z; acc[3] += kv * qv.w;
        }
        int mmv = mmp[mbase + si];
#pragma unroll
        for (int v = 0; v < 4; ++v) {
            int j = sjg * 4 + v;
            float s = mmv ? acc[v] * P_SCALAR : NEG_INF;
            Ps[si][j] = __expf(s - cm[j]) * rs[j];
        }

        // V chunks: 4 x (128 rows of Dv)
#pragma unroll
        for (int c = 0; c < 4; ++c) {
            __syncthreads();  // P ready (c==0) / previous Vs consumed
            for (int l = t; l < 64 * 128; l += 256) {
                int i = l & 63, r = l >> 6;
                Vs[i][r] = vp[(size_t)(c * 128 + r) * NM + mbase + i];
            }
            __syncthreads();
            for (int i = 0; i < 64; ++i) {
                float p = Ps[i][aj];
                float4 v0 = *(const float4*)&Vs[i][adv * 8];
                float4 v1 = *(const float4*)&Vs[i][adv * 8 + 4];
                O[c * 8 + 0] += p * v0.x; O[c * 8 + 1] += p * v0.y;
                O[c * 8 + 2] += p * v0.z; O[c * 8 + 3] += p * v0.w;
                O[c * 8 + 4] += p * v1.x; O[c * 8 + 5] += p * v1.y;
                O[c * 8 + 6] += p * v1.z; O[c * 8 + 7] += p * v1.w;
            }
        }
        __syncthreads();  // Ps consumed before next tile overwrites
    }

    const int anyflag = (flags[b * 2] != 0) && (flags[b * 2 + 1] != 0);
    const int q = qbase + aj;
    const bool valid = anyflag && (qmask[b * NQ + q] != 0);
#pragma unroll
    for (int c = 0; c < 4; ++c)
#pragma unroll
        for (int k = 0; k < 8; ++k) {
            int dv = c * 128 + adv * 8 + k;
            out[(size_t)(b * DV + dv) * NQ + q] = valid ? O[c * 8 + k] : 0.0f;
        }
}

// ---------------------------------------------------------------------------
extern "C" void kernel_launch(void* const* d_in, const int* in_sizes, int n_in,
                              void* d_out, int out_size, void* d_ws, size_t ws_size,
                              hipStream_t stream) {
    const float* qkey  = (const float*)d_in[0];
    // d_in[1] (qval) is unused by the reference
    const int*   qmask = (const int*)d_in[2];
    const float* mkey  = (const float*)d_in[3];
    const float* mval  = (const float*)d_in[4];
    const int*   mmask = (const int*)d_in[5];
    float* out = (float*)d_out;

    float* colmax = (float*)d_ws;
    float* colsum = colmax + BATCH * NQ;
    int*   flags  = (int*)(colsum + BATCH * NQ);

    flags_kernel<<<BATCH, 256, 0, stream>>>(qmask, mmask, flags);

    dim3 g1(NQ / 32, BATCH);
    pass1_kernel<<<g1, 256, 0, stream>>>(qkey, mkey, mmask, colmax, colsum);

    dim3 g2(NQ / 16, BATCH);
    pass2_kernel<<<g2, 256, 0, stream>>>(qkey, mkey, mval, qmask, mmask, flags,
                                         colmax, colsum, out);
}

// Round 2
// 695.893 us; speedup vs baseline: 107.9437x; 107.9437x over previous
//
#include <hip/hip_runtime.h>

#define NQ 4096
#define NM 8192
#define DK 128
#define DV 512
#define BATCH 2

typedef __attribute__((ext_vector_type(8))) short short8;
typedef __attribute__((ext_vector_type(4))) float f32x4;
typedef unsigned short ushort_t;

// round-to-nearest-even fp32 -> bf16 bits
static __device__ __forceinline__ unsigned short f2bf(float x) {
    union { float f; unsigned int u; } c; c.f = x;
    unsigned int u = c.u;
    unsigned int r = (u + 0x7FFFu + ((u >> 16) & 1u)) >> 16;
    return (unsigned short)r;
}
static __device__ __forceinline__ float bf2f(unsigned short h) {
    union { unsigned int u; float f; } c; c.u = ((unsigned int)h) << 16;
    return c.f;
}

// ---------------------------------------------------------------------------
// flags: per-batch any(qmask), any(mmask)
// ---------------------------------------------------------------------------
__global__ void flags_kernel(const int* __restrict__ qmask,
                             const int* __restrict__ mmask,
                             int* __restrict__ flags) {
    const int b = blockIdx.x;
    __shared__ int aq, am;
    if (threadIdx.x == 0) { aq = 0; am = 0; }
    __syncthreads();
    int lq = 0, lm = 0;
    for (int i = threadIdx.x; i < NQ; i += blockDim.x) lq |= (qmask[b * NQ + i] != 0);
    for (int i = threadIdx.x; i < NM; i += blockDim.x) lm |= (mmask[b * NM + i] != 0);
    if (lq) atomicOr(&aq, 1);
    if (lm) atomicOr(&am, 1);
    __syncthreads();
    if (threadIdx.x == 0) { flags[b * 2 + 0] = aq; flags[b * 2 + 1] = am; }
}

// ---------------------------------------------------------------------------
// prep: transpose [B][DK][N] fp32 -> [B][N][DK] bf16 hi/lo (split precision)
// ---------------------------------------------------------------------------
__global__ __launch_bounds__(256) void prep_tsp_kernel(
    const float* __restrict__ src, ushort_t* __restrict__ hi,
    ushort_t* __restrict__ lo, int N) {
    const int b = blockIdx.z;
    const int d0 = blockIdx.y * 32;
    const int n0 = blockIdx.x * 32;
    __shared__ float t32[32][33];
    for (int l = threadIdx.x; l < 1024; l += 256) {
        int r = l >> 5, c = l & 31;
        t32[r][c] = src[((size_t)b * DK + d0 + r) * N + n0 + c];
    }
    __syncthreads();
    for (int l = threadIdx.x; l < 1024; l += 256) {
        int r = l >> 5, c = l & 31;   // r: n, c: d
        float f = t32[c][r];
        unsigned short h = f2bf(f);
        unsigned short lw = f2bf(f - bf2f(h));
        size_t off = ((size_t)b * N + n0 + r) * DK + d0 + c;
        hi[off] = h;
        lo[off] = lw;
    }
}

// ---------------------------------------------------------------------------
// prep: elementwise fp32 -> bf16 (V stays [B][DV][NM], m-contiguous)
// ---------------------------------------------------------------------------
__global__ __launch_bounds__(256) void prep_v_kernel(
    const float* __restrict__ src, ushort_t* __restrict__ dst) {
    size_t i4 = (size_t)blockIdx.x * 256 + threadIdx.x;  // x4 elements
    const float4 v = *(const float4*)(src + i4 * 4);
    ushort4 o;
    o.x = f2bf(v.x); o.y = f2bf(v.y); o.z = f2bf(v.z); o.w = f2bf(v.w);
    *(ushort4*)(dst + i4 * 4) = o;
}

// ---------------------------------------------------------------------------
// main: flash attention with split-bf16 QK^T and bf16 PV (MFMA 16x16x32)
// block = 256 (4 waves); q-tile 32; m-tile 64; dv-chunk 128 (grid.y = 4)
// ---------------------------------------------------------------------------
__global__ __launch_bounds__(256, 2) void attn_main_kernel(
    const ushort_t* __restrict__ Qhi, const ushort_t* __restrict__ Qlo,
    const ushort_t* __restrict__ Khi, const ushort_t* __restrict__ Klo,
    const ushort_t* __restrict__ Vb,
    const int* __restrict__ qmask, const int* __restrict__ mmask,
    const int* __restrict__ flags, float* __restrict__ out) {
    const int t = threadIdx.x;
    const int lane = t & 63;
    const int w = t >> 6;          // wave 0..3
    const int quad = lane >> 4;    // 0..3
    const int col = lane & 15;     // 0..15
    const int qb = blockIdx.x * 32;
    const int dvb = blockIdx.y * 128;
    const int b = blockIdx.z;

    __shared__ __align__(16) ushort_t Kh_s[64][136];  // [m][d+8 pad]
    __shared__ __align__(16) ushort_t Kl_s[64][136];
    __shared__ __align__(16) ushort_t V_s[128][72];   // [v][m+8 pad]
    __shared__ __align__(16) ushort_t P_s[32][72];    // [q][m+8 pad]
    __shared__ float tmax_s[4][32], tsum_s[4][32];
    __shared__ float mrun[32], lrun[32];

    // resident Q fragments (B-operand: lane holds Q[d=ks*32+quad*8+j][q=col])
    short8 qfh[2][4], qfl[2][4];
    {
        const ushort_t* qhp = Qhi + ((size_t)b * NQ + qb) * DK;
        const ushort_t* qlp = Qlo + ((size_t)b * NQ + qb) * DK;
#pragma unroll
        for (int qt = 0; qt < 2; ++qt)
#pragma unroll
            for (int ks = 0; ks < 4; ++ks) {
                size_t off = (size_t)(qt * 16 + col) * DK + ks * 32 + quad * 8;
                qfh[qt][ks] = *(const short8*)(qhp + off);
                qfl[qt][ks] = *(const short8*)(qlp + off);
            }
    }

    if (t < 32) { mrun[t] = -3.0e38f; lrun[t] = 0.0f; }

    const f32x4 zero4 = {0.f, 0.f, 0.f, 0.f};
    f32x4 accO[2][2];  // [vt][qt]
#pragma unroll
    for (int vt = 0; vt < 2; ++vt)
#pragma unroll
        for (int qt = 0; qt < 2; ++qt) accO[vt][qt] = zero4;

    const ushort_t* kh = Khi + (size_t)b * NM * DK;
    const ushort_t* kl = Klo + (size_t)b * NM * DK;
    const ushort_t* vg = Vb + ((size_t)b * DV + dvb) * NM;
    const int* mmp = mmask + b * NM;

    for (int mb = 0; mb < NM; mb += 64) {
        // ---- stage K hi/lo (64x128 bf16 each) + V (128x64 bf16) ----
        {
            const int row = t >> 4, c16 = (t & 15) * 8;
#pragma unroll
            for (int i = 0; i < 4; ++i) {
                int r2 = row + i * 16;
                *(short8*)&Kh_s[r2][c16] = *(const short8*)(kh + (size_t)(mb + r2) * DK + c16);
                *(short8*)&Kl_s[r2][c16] = *(const short8*)(kl + (size_t)(mb + r2) * DK + c16);
            }
            const int vr = t >> 3, mc = (t & 7) * 8;
#pragma unroll
            for (int i = 0; i < 4; ++i) {
                int r2 = vr + i * 32;
                *(short8*)&V_s[r2][mc] = *(const short8*)(vg + (size_t)r2 * NM + mb + mc);
            }
        }
        __syncthreads();  // A: staging visible

        // ---- S = K^T Q (wave w owns m rows [w*16, w*16+16)) ----
        f32x4 accS[2];
        accS[0] = zero4; accS[1] = zero4;
#pragma unroll
        for (int ks = 0; ks < 4; ++ks) {
            short8 ah = *(const short8*)&Kh_s[w * 16 + col][ks * 32 + quad * 8];
            short8 al = *(const short8*)&Kl_s[w * 16 + col][ks * 32 + quad * 8];
#pragma unroll
            for (int qt = 0; qt < 2; ++qt) {
                accS[qt] = __builtin_amdgcn_mfma_f32_16x16x32_bf16(ah, qfh[qt][ks], accS[qt], 0, 0, 0);
                accS[qt] = __builtin_amdgcn_mfma_f32_16x16x32_bf16(ah, qfl[qt][ks], accS[qt], 0, 0, 0);
                accS[qt] = __builtin_amdgcn_mfma_f32_16x16x32_bf16(al, qfh[qt][ks], accS[qt], 0, 0, 0);
            }
        }

        // ---- mask + scale + per-tile column max ----
        float s[2][4];
        const int mrow = mb + w * 16 + quad * 4;
        int msk[4];
#pragma unroll
        for (int r = 0; r < 4; ++r) msk[r] = mmp[mrow + r];
#pragma unroll
        for (int qt = 0; qt < 2; ++qt) {
            float tm = -3.0e38f;
#pragma unroll
            for (int r = 0; r < 4; ++r) {
                s[qt][r] = msk[r] ? accS[qt][r] * 40.0f : -1e9f;
                tm = fmaxf(tm, s[qt][r]);
            }
            tm = fmaxf(tm, __shfl_xor(tm, 16, 64));
            tm = fmaxf(tm, __shfl_xor(tm, 32, 64));
            if (lane < 16) tmax_s[w][qt * 16 + col] = tm;
        }
        __syncthreads();  // B: tile maxes visible

        // ---- new running max + rescale factor (every thread, both q-tiles) ----
        float mnew[2], alpha[2];
#pragma unroll
        for (int qt = 0; qt < 2; ++qt) {
            int q = qt * 16 + col;
            float mo = mrun[q];
            float mn = fmaxf(fmaxf(tmax_s[0][q], tmax_s[1][q]),
                             fmaxf(tmax_s[2][q], tmax_s[3][q]));
            mn = fmaxf(mn, mo);
            mnew[qt] = mn;
            alpha[qt] = __expf(mo - mn);
        }

        // ---- P = exp(s - mnew), tile sums, store P to LDS, rescale O ----
#pragma unroll
        for (int qt = 0; qt < 2; ++qt) {
            float ps = 0.f;
#pragma unroll
            for (int r = 0; r < 4; ++r) {
                float p = __expf(s[qt][r] - mnew[qt]);
                ps += p;
                P_s[qt * 16 + col][w * 16 + quad * 4 + r] = f2bf(p);
            }
            ps += __shfl_xor(ps, 16, 64);
            ps += __shfl_xor(ps, 32, 64);
            if (lane < 16) tsum_s[w][qt * 16 + col] = ps;
#pragma unroll
            for (int vt = 0; vt < 2; ++vt)
#pragma unroll
                for (int r = 0; r < 4; ++r) accO[vt][qt][r] *= alpha[qt];
        }
        __syncthreads();  // D: P visible

        // ---- O += V * P (wave w owns v tiles 2w, 2w+1) ----
#pragma unroll
        for (int ks = 0; ks < 2; ++ks) {
            short8 bp[2];
#pragma unroll
            for (int qt = 0; qt < 2; ++qt)
                bp[qt] = *(const short8*)&P_s[qt * 16 + col][ks * 32 + quad * 8];
#pragma unroll
            for (int vt = 0; vt < 2; ++vt) {
                short8 av = *(const short8*)&V_s[(w * 2 + vt) * 16 + col][ks * 32 + quad * 8];
#pragma unroll
                for (int qt = 0; qt < 2; ++qt)
                    accO[vt][qt] = __builtin_amdgcn_mfma_f32_16x16x32_bf16(av, bp[qt], accO[vt][qt], 0, 0, 0);
            }
        }

        // ---- running stats update (q = t for t < 32) ----
        if (t < 32) {
            float l = lrun[t] * alpha[t >> 4] +
                      tsum_s[0][t] + tsum_s[1][t] + tsum_s[2][t] + tsum_s[3][t];
            lrun[t] = l;
            mrun[t] = mnew[t >> 4];
        }
        __syncthreads();  // E: stats/LDS safe to overwrite next iter
    }

    // ---- epilogue: divide by l, gate by masks, write ----
    const int fq = flags[b * 2], fm = flags[b * 2 + 1];
#pragma unroll
    for (int qt = 0; qt < 2; ++qt) {
        int q = qb + qt * 16 + col;
        float rinv = 1.0f / lrun[qt * 16 + col];
        bool valid = fq && fm && (qmask[b * NQ + q] != 0);
        float g = valid ? rinv : 0.0f;
#pragma unroll
        for (int vt = 0; vt < 2; ++vt)
#pragma unroll
            for (int r = 0; r < 4; ++r) {
                int v = dvb + (w * 2 + vt) * 16 + quad * 4 + r;
                out[((size_t)b * DV + v) * NQ + q] = accO[vt][qt][r] * g;
            }
    }
}

// ---------------------------------------------------------------------------
extern "C" void kernel_launch(void* const* d_in, const int* in_sizes, int n_in,
                              void* d_out, int out_size, void* d_ws, size_t ws_size,
                              hipStream_t stream) {
    const float* qkey  = (const float*)d_in[0];
    // d_in[1] (qval) unused by the reference
    const int*   qmask = (const int*)d_in[2];
    const float* mkey  = (const float*)d_in[3];
    const float* mval  = (const float*)d_in[4];
    const int*   mmask = (const int*)d_in[5];
    float* out = (float*)d_out;

    // workspace layout (bytes)
    char* ws = (char*)d_ws;
    const size_t QS = (size_t)BATCH * NQ * DK * 2;  // 2 MB
    const size_t KS = (size_t)BATCH * NM * DK * 2;  // 4 MB
    const size_t VS = (size_t)BATCH * DV * NM * 2;  // 16 MB
    ushort_t* Qhi = (ushort_t*)(ws);
    ushort_t* Qlo = (ushort_t*)(ws + QS);
    ushort_t* Khi = (ushort_t*)(ws + 2 * QS);
    ushort_t* Klo = (ushort_t*)(ws + 2 * QS + KS);
    ushort_t* Vb  = (ushort_t*)(ws + 2 * QS + 2 * KS);
    int* flags    = (int*)(ws + 2 * QS + 2 * KS + VS);

    flags_kernel<<<BATCH, 256, 0, stream>>>(qmask, mmask, flags);

    dim3 gq(NQ / 32, DK / 32, BATCH);
    prep_tsp_kernel<<<gq, 256, 0, stream>>>(qkey, Qhi, Qlo, NQ);
    dim3 gk(NM / 32, DK / 32, BATCH);
    prep_tsp_kernel<<<gk, 256, 0, stream>>>(mkey, Khi, Klo, NM);

    const int vblocks = (int)(((size_t)BATCH * DV * NM) / (256 * 4));
    prep_v_kernel<<<vblocks, 256, 0, stream>>>(mval, Vb);

    dim3 gm(NQ / 32, DV / 128, BATCH);
    attn_main_kernel<<<gm, 256, 0, stream>>>(Qhi, Qlo, Khi, Klo, Vb,
                                             qmask, mmask, flags, out);
}

// Round 3
// 598.531 us; speedup vs baseline: 125.5027x; 1.1627x over previous
//
#include <hip/hip_runtime.h>

#define NQ 4096
#define NM 8192
#define DK 128
#define DV 512
#define BATCH 2

typedef __attribute__((ext_vector_type(8))) short short8;
typedef __attribute__((ext_vector_type(4))) float f32x4;
typedef unsigned short ushort_t;

static __device__ __forceinline__ unsigned short f2bf(float x) {
    union { float f; unsigned int u; } c; c.f = x;
    unsigned int u = c.u;
    return (unsigned short)((u + 0x7FFFu + ((u >> 16) & 1u)) >> 16);
}
static __device__ __forceinline__ float bf2f(unsigned short h) {
    union { unsigned int u; float f; } c; c.u = ((unsigned int)h) << 16;
    return c.f;
}

// ---------------------------------------------------------------------------
// flags: per-batch any(qmask), any(mmask)
// ---------------------------------------------------------------------------
__global__ void flags_kernel(const int* __restrict__ qmask,
                             const int* __restrict__ mmask,
                             int* __restrict__ flags) {
    const int b = blockIdx.x;
    __shared__ int aq, am;
    if (threadIdx.x == 0) { aq = 0; am = 0; }
    __syncthreads();
    int lq = 0, lm = 0;
    for (int i = threadIdx.x; i < NQ; i += blockDim.x) lq |= (qmask[b * NQ + i] != 0);
    for (int i = threadIdx.x; i < NM; i += blockDim.x) lm |= (mmask[b * NM + i] != 0);
    if (lq) atomicOr(&aq, 1);
    if (lm) atomicOr(&am, 1);
    __syncthreads();
    if (threadIdx.x == 0) { flags[b * 2 + 0] = aq; flags[b * 2 + 1] = am; }
}

// ---------------------------------------------------------------------------
// prep: transpose [B][DK][N] fp32 -> [B][N][DK] bf16 hi/lo (split precision)
// ---------------------------------------------------------------------------
__global__ __launch_bounds__(256) void prep_tsp_kernel(
    const float* __restrict__ src, ushort_t* __restrict__ hi,
    ushort_t* __restrict__ lo, int N) {
    const int b = blockIdx.z;
    const int d0 = blockIdx.y * 32;
    const int n0 = blockIdx.x * 32;
    __shared__ float t32[32][33];
    for (int l = threadIdx.x; l < 1024; l += 256) {
        int r = l >> 5, c = l & 31;
        t32[r][c] = src[((size_t)b * DK + d0 + r) * N + n0 + c];
    }
    __syncthreads();
    for (int l = threadIdx.x; l < 1024; l += 256) {
        int r = l >> 5, c = l & 31;   // r: n, c: d
        float f = t32[c][r];
        unsigned short h = f2bf(f);
        unsigned short lw = f2bf(f - bf2f(h));
        size_t off = ((size_t)b * N + n0 + r) * DK + d0 + c;
        hi[off] = h;
        lo[off] = lw;
    }
}

// ---------------------------------------------------------------------------
// prep: elementwise fp32 -> bf16 (V stays [B][DV][NM], m-contiguous)
// ---------------------------------------------------------------------------
__global__ __launch_bounds__(256) void prep_v_kernel(
    const float* __restrict__ src, ushort_t* __restrict__ dst) {
    size_t i4 = (size_t)blockIdx.x * 256 + threadIdx.x;
    const float4 v = *(const float4*)(src + i4 * 4);
    ushort4 o;
    o.x = f2bf(v.x); o.y = f2bf(v.y); o.z = f2bf(v.z); o.w = f2bf(v.w);
    *(ushort4*)(dst + i4 * 4) = o;
}

// ---------------------------------------------------------------------------
// main: flash attention, K/V global->register A-frags (no LDS staging),
// P via LDS. q-tile 32, m-tile 128, 512 threads (8 waves), 2 barriers/iter.
// wave w: S rows m=[16w,16w+16); PV dv rows [64w, 64w+64).
// ---------------------------------------------------------------------------
__global__ __launch_bounds__(512, 2) void attn_main_kernel(
    const ushort_t* __restrict__ Qhi, const ushort_t* __restrict__ Qlo,
    const ushort_t* __restrict__ Khi, const ushort_t* __restrict__ Klo,
    const ushort_t* __restrict__ Vb,
    const int* __restrict__ qmask, const int* __restrict__ mmask,
    const int* __restrict__ flags, float* __restrict__ out) {
    const int t = threadIdx.x;
    const int lane = t & 63;
    const int w = t >> 6;          // wave 0..7
    const int quad = lane >> 4;    // 0..3
    const int col = lane & 15;     // 0..15
    const int qb = blockIdx.x * 32;
    const int b = blockIdx.y;

    __shared__ __align__(16) ushort_t P_s[32][136];   // [q][m], pad 8
    __shared__ float tmax_s[8][32], tsum_s[8][32];
    __shared__ float mrun[32], lrun[32];

    // resident Q fragments (B-operand: lane holds Q[q=col][k=quad*8+j])
    short8 qfh[2][4], qfl[2][4];
    {
        const ushort_t* qhp = Qhi + ((size_t)b * NQ + qb) * DK;
        const ushort_t* qlp = Qlo + ((size_t)b * NQ + qb) * DK;
#pragma unroll
        for (int qt = 0; qt < 2; ++qt)
#pragma unroll
            for (int ks = 0; ks < 4; ++ks) {
                size_t off = (size_t)(qt * 16 + col) * DK + ks * 32 + quad * 8;
                qfh[qt][ks] = *(const short8*)(qhp + off);
                qfl[qt][ks] = *(const short8*)(qlp + off);
            }
    }

    if (t < 32) { mrun[t] = -3.0e38f; lrun[t] = 0.0f; }

    // per-lane base pointers
    const ushort_t* khp = Khi + ((size_t)b * NM + w * 16 + col) * DK + quad * 8;
    const ushort_t* klp = Klo + ((size_t)b * NM + w * 16 + col) * DK + quad * 8;
    const ushort_t* vp  = Vb + ((size_t)b * DV + w * 64 + col) * NM + quad * 8;
    const int* mmp = mmask + b * NM + w * 16 + quad * 4;

    const f32x4 zero4 = {0.f, 0.f, 0.f, 0.f};
    f32x4 accO[4][2];
#pragma unroll
    for (int vt = 0; vt < 4; ++vt)
#pragma unroll
        for (int qt = 0; qt < 2; ++qt) accO[vt][qt] = zero4;

    for (int it = 0; it < NM / 128; ++it) {
        const int mb = it * 128;

        // ---- phase A: QK (split bf16), K frags straight from global ----
        f32x4 accS[2];
        accS[0] = zero4; accS[1] = zero4;
#pragma unroll
        for (int ks = 0; ks < 4; ++ks) {
            short8 ah = *(const short8*)(khp + (size_t)mb * DK + ks * 32);
            short8 al = *(const short8*)(klp + (size_t)mb * DK + ks * 32);
            accS[0] = __builtin_amdgcn_mfma_f32_16x16x32_bf16(ah, qfh[0][ks], accS[0], 0, 0, 0);
            accS[1] = __builtin_amdgcn_mfma_f32_16x16x32_bf16(ah, qfh[1][ks], accS[1], 0, 0, 0);
            accS[0] = __builtin_amdgcn_mfma_f32_16x16x32_bf16(ah, qfl[0][ks], accS[0], 0, 0, 0);
            accS[1] = __builtin_amdgcn_mfma_f32_16x16x32_bf16(ah, qfl[1][ks], accS[1], 0, 0, 0);
            accS[0] = __builtin_amdgcn_mfma_f32_16x16x32_bf16(al, qfh[0][ks], accS[0], 0, 0, 0);
            accS[1] = __builtin_amdgcn_mfma_f32_16x16x32_bf16(al, qfh[1][ks], accS[1], 0, 0, 0);
        }

        // ---- phase B: mask, scale, per-wave column max ----
        const int4 mv = *(const int4*)(mmp + mb);
        const int mskr[4] = {mv.x, mv.y, mv.z, mv.w};
        float s[2][4];
#pragma unroll
        for (int qt = 0; qt < 2; ++qt) {
            float tm = -3.0e38f;
#pragma unroll
            for (int r = 0; r < 4; ++r) {
                s[qt][r] = mskr[r] ? accS[qt][r] * 40.0f : -1e9f;
                tm = fmaxf(tm, s[qt][r]);
            }
            tm = fmaxf(tm, __shfl_xor(tm, 16, 64));
            tm = fmaxf(tm, __shfl_xor(tm, 32, 64));
            if (lane < 16) tmax_s[w][qt * 16 + col] = tm;
        }
        __syncthreads();  // sync1: tmax visible; prev-iter P reads done

        // ---- phase C: softmax, P->LDS, rescale O ----
        float mnew[2], alpha[2];
#pragma unroll
        for (int qt = 0; qt < 2; ++qt) {
            int q = qt * 16 + col;
            float mo = mrun[q];
            float mn = mo;
#pragma unroll
            for (int ww = 0; ww < 8; ++ww) mn = fmaxf(mn, tmax_s[ww][q]);
            mnew[qt] = mn;
            alpha[qt] = __expf(mo - mn);
        }
#pragma unroll
        for (int qt = 0; qt < 2; ++qt) {
            float p0 = __expf(s[qt][0] - mnew[qt]);
            float p1 = __expf(s[qt][1] - mnew[qt]);
            float p2 = __expf(s[qt][2] - mnew[qt]);
            float p3 = __expf(s[qt][3] - mnew[qt]);
            ushort4 pk;
            pk.x = f2bf(p0); pk.y = f2bf(p1); pk.z = f2bf(p2); pk.w = f2bf(p3);
            *(ushort4*)&P_s[qt * 16 + col][w * 16 + quad * 4] = pk;
            float ps = p0 + p1 + p2 + p3;
            ps += __shfl_xor(ps, 16, 64);
            ps += __shfl_xor(ps, 32, 64);
            if (lane < 16) tsum_s[w][qt * 16 + col] = ps;
#pragma unroll
            for (int vt = 0; vt < 4; ++vt)
#pragma unroll
                for (int r = 0; r < 4; ++r) accO[vt][qt][r] *= alpha[qt];
        }
        __syncthreads();  // sync2: P + tsum visible

        // ---- phase D: stats update + PV (V frags straight from global) ----
        if (t < 32) {
            float mo = mrun[t], mn = mo;
#pragma unroll
            for (int ww = 0; ww < 8; ++ww) mn = fmaxf(mn, tmax_s[ww][t]);
            float sm = 0.f;
#pragma unroll
            for (int ww = 0; ww < 8; ++ww) sm += tsum_s[ww][t];
            lrun[t] = lrun[t] * __expf(mo - mn) + sm;
            mrun[t] = mn;
        }
#pragma unroll
        for (int ks = 0; ks < 4; ++ks) {
            short8 b0 = *(const short8*)&P_s[col][ks * 32 + quad * 8];
            short8 b1 = *(const short8*)&P_s[16 + col][ks * 32 + quad * 8];
#pragma unroll
            for (int vt = 0; vt < 4; ++vt) {
                short8 av = *(const short8*)(vp + (size_t)vt * 16 * NM + mb + ks * 32);
                accO[vt][0] = __builtin_amdgcn_mfma_f32_16x16x32_bf16(av, b0, accO[vt][0], 0, 0, 0);
                accO[vt][1] = __builtin_amdgcn_mfma_f32_16x16x32_bf16(av, b1, accO[vt][1], 0, 0, 0);
            }
        }
        // no trailing barrier: next-iter sync1/sync2 protect P_s & stats
    }
    __syncthreads();  // final stats visible

    // ---- epilogue ----
    const int fgate = (flags[b * 2] != 0) && (flags[b * 2 + 1] != 0);
#pragma unroll
    for (int qt = 0; qt < 2; ++qt) {
        int q = qb + qt * 16 + col;
        float rinv = 1.0f / lrun[qt * 16 + col];
        bool valid = fgate && (qmask[b * NQ + q] != 0);
        float g = valid ? rinv : 0.0f;
#pragma unroll
        for (int vt = 0; vt < 4; ++vt)
#pragma unroll
            for (int r = 0; r < 4; ++r) {
                int dv = w * 64 + vt * 16 + quad * 4 + r;
                out[((size_t)b * DV + dv) * NQ + q] = accO[vt][qt][r] * g;
            }
    }
}

// ---------------------------------------------------------------------------
extern "C" void kernel_launch(void* const* d_in, const int* in_sizes, int n_in,
                              void* d_out, int out_size, void* d_ws, size_t ws_size,
                              hipStream_t stream) {
    const float* qkey  = (const float*)d_in[0];
    // d_in[1] (qval) unused by the reference
    const int*   qmask = (const int*)d_in[2];
    const float* mkey  = (const float*)d_in[3];
    const float* mval  = (const float*)d_in[4];
    const int*   mmask = (const int*)d_in[5];
    float* out = (float*)d_out;

    char* ws = (char*)d_ws;
    const size_t QS = (size_t)BATCH * NQ * DK * 2;
    const size_t KS = (size_t)BATCH * NM * DK * 2;
    const size_t VS = (size_t)BATCH * DV * NM * 2;
    ushort_t* Qhi = (ushort_t*)(ws);
    ushort_t* Qlo = (ushort_t*)(ws + QS);
    ushort_t* Khi = (ushort_t*)(ws + 2 * QS);
    ushort_t* Klo = (ushort_t*)(ws + 2 * QS + KS);
    ushort_t* Vb  = (ushort_t*)(ws + 2 * QS + 2 * KS);
    int* flags    = (int*)(ws + 2 * QS + 2 * KS + VS);

    flags_kernel<<<BATCH, 256, 0, stream>>>(qmask, mmask, flags);

    dim3 gq(NQ / 32, DK / 32, BATCH);
    prep_tsp_kernel<<<gq, 256, 0, stream>>>(qkey, Qhi, Qlo, NQ);
    dim3 gk(NM / 32, DK / 32, BATCH);
    prep_tsp_kernel<<<gk, 256, 0, stream>>>(mkey, Khi, Klo, NM);

    const int vblocks = (int)(((size_t)BATCH * DV * NM) / (256 * 4));
    prep_v_kernel<<<vblocks, 256, 0, stream>>>(mval, Vb);

    dim3 gm(NQ / 32, BATCH);
    attn_main_kernel<<<gm, 512, 0, stream>>>(Qhi, Qlo, Khi, Klo, Vb,
                                             qmask, mmask, flags, out);
}

// Round 4
// 400.369 us; speedup vs baseline: 187.6200x; 1.4949x over previous
//
#include <hip/hip_runtime.h>

#define NQ 4096
#define NM 8192
#define DK 128
#define DV 512
#define BATCH 2

typedef __attribute__((ext_vector_type(8))) short short8;
typedef __attribute__((ext_vector_type(4))) float f32x4;
typedef unsigned short ushort_t;

static __device__ __forceinline__ unsigned short f2bf(float x) {
    union { float f; unsigned int u; } c; c.f = x;
    unsigned int u = c.u;
    return (unsigned short)((u + 0x7FFFu + ((u >> 16) & 1u)) >> 16);
}
static __device__ __forceinline__ float bf2f(unsigned short h) {
    union { unsigned int u; float f; } c; c.u = ((unsigned int)h) << 16;
    return c.f;
}

// ---------------------------------------------------------------------------
// scan: per-batch compaction of mmask.
//   cidx[b][i'] = original m of i'-th valid row (stable order)
//   cpos[b][m]  = exclusive prefix (compacted slot if valid)
//   cnts[b]     = number of valid rows;  qflags[b] = any(qmask[b])
// one block per batch, 256 threads x 32 elems.
// ---------------------------------------------------------------------------
__global__ __launch_bounds__(256) void scan_kernel(
    const int* __restrict__ qmask, const int* __restrict__ mmask,
    int* __restrict__ cidx, int* __restrict__ cpos,
    int* __restrict__ cnts, int* __restrict__ qflags) {
    const int b = blockIdx.x;
    const int t = threadIdx.x;
    __shared__ int ls[256];
    __shared__ int qsh;

    const int* mp = mmask + b * NM;
    const int base = t * 32;
    int c = 0;
#pragma unroll
    for (int i = 0; i < 32; ++i) c += (mp[base + i] != 0);
    ls[t] = c;
    if (t == 0) qsh = 0;
    __syncthreads();
    // inclusive Hillis-Steele scan over 256 counts
    for (int off = 1; off < 256; off <<= 1) {
        int v = (t >= off) ? ls[t - off] : 0;
        __syncthreads();
        ls[t] += v;
        __syncthreads();
    }
    const int excl = ls[t] - c;
    const int total = ls[255];

    int run = excl;
    for (int i = 0; i < 32; ++i) {
        int m = base + i;
        int valid = (mp[m] != 0);
        cpos[b * NM + m] = run;
        if (valid) { cidx[b * NM + run] = m; ++run; }
    }

    int qa = 0;
    for (int i = t; i < NQ; i += 256) qa |= (qmask[b * NQ + i] != 0);
    if (qa) atomicOr(&qsh, 1);
    __syncthreads();
    if (t == 0) { cnts[b] = total; qflags[b] = qsh; }
}

// ---------------------------------------------------------------------------
// prep Q: transpose [B][DK][NQ] fp32 -> [B][q][DK] bf16 hi/lo
// ---------------------------------------------------------------------------
__global__ __launch_bounds__(256) void prep_q_kernel(
    const float* __restrict__ src, ushort_t* __restrict__ hi,
    ushort_t* __restrict__ lo) {
    const int b = blockIdx.z;
    const int d0 = blockIdx.y * 32;
    const int n0 = blockIdx.x * 32;
    __shared__ float t32[32][33];
    for (int l = threadIdx.x; l < 1024; l += 256) {
        int r = l >> 5, c = l & 31;
        t32[r][c] = src[((size_t)b * DK + d0 + r) * NQ + n0 + c];
    }
    __syncthreads();
    for (int l = threadIdx.x; l < 1024; l += 256) {
        int r = l >> 5, c = l & 31;   // r: q, c: d
        float f = t32[c][r];
        unsigned short h = f2bf(f);
        unsigned short lw = f2bf(f - bf2f(h));
        size_t off = ((size_t)b * NQ + n0 + r) * DK + d0 + c;
        hi[off] = h;
        lo[off] = lw;
    }
}

// ---------------------------------------------------------------------------
// prep K: transpose + COMPACTING gather [B][DK][NM] -> [B][m'][DK] hi/lo
// ---------------------------------------------------------------------------
__global__ __launch_bounds__(256) void prep_k_kernel(
    const float* __restrict__ src, const int* __restrict__ mmask,
    const int* __restrict__ cpos,
    ushort_t* __restrict__ hi, ushort_t* __restrict__ lo) {
    const int b = blockIdx.z;
    const int d0 = blockIdx.y * 32;
    const int n0 = blockIdx.x * 32;
    __shared__ float t32[32][33];
    for (int l = threadIdx.x; l < 1024; l += 256) {
        int r = l >> 5, c = l & 31;
        t32[r][c] = src[((size_t)b * DK + d0 + r) * NM + n0 + c];
    }
    __syncthreads();
    for (int l = threadIdx.x; l < 1024; l += 256) {
        int r = l >> 5, c = l & 31;   // r: m, c: d
        int m = n0 + r;
        if (mmask[b * NM + m] != 0) {
            int pos = cpos[b * NM + m];
            float f = t32[c][r];
            unsigned short h = f2bf(f);
            unsigned short lw = f2bf(f - bf2f(h));
            size_t off = ((size_t)b * NM + pos) * DK + d0 + c;
            hi[off] = h;
            lo[off] = lw;
        }
    }
}

// ---------------------------------------------------------------------------
// prep V: compacting gather + convert [B][DV][NM] fp32 -> [B][DV][m'] bf16
// pads [cnt, NM) with zeros.
// ---------------------------------------------------------------------------
__global__ __launch_bounds__(256) void prep_v_kernel(
    const float* __restrict__ src, const int* __restrict__ cidx,
    const int* __restrict__ cnts, ushort_t* __restrict__ dst) {
    const size_t idx = (size_t)blockIdx.x * 256 + threadIdx.x;
    const int mi4 = (int)((idx % (NM / 4)) * 4);
    const int dv = (int)((idx / (NM / 4)) % DV);
    const int b = (int)(idx / ((size_t)(NM / 4) * DV));
    const int cnt = cnts[b];

    int4 ci = *(const int4*)(cidx + b * NM + mi4);
    int i0 = (mi4 + 0 < cnt) ? ci.x : 0;
    int i1 = (mi4 + 1 < cnt) ? ci.y : 0;
    int i2 = (mi4 + 2 < cnt) ? ci.z : 0;
    int i3 = (mi4 + 3 < cnt) ? ci.w : 0;
    const float* row = src + ((size_t)b * DV + dv) * NM;
    ushort4 o;
    o.x = (mi4 + 0 < cnt) ? f2bf(row[i0]) : (ushort_t)0;
    o.y = (mi4 + 1 < cnt) ? f2bf(row[i1]) : (ushort_t)0;
    o.z = (mi4 + 2 < cnt) ? f2bf(row[i2]) : (ushort_t)0;
    o.w = (mi4 + 3 < cnt) ? f2bf(row[i3]) : (ushort_t)0;
    *(ushort4*)(dst + ((size_t)b * DV + dv) * NM + mi4) = o;
}

// ---------------------------------------------------------------------------
// main: flash attention over COMPACTED memory rows, m-split into 2 halves.
// q-tile 32, m-tile 128, 512 threads (8 waves). Emits unnormalized O' (bf16)
// + per-q running (m, l). wave w: S rows [16w,16w+16); PV dv [64w,64w+64).
// ---------------------------------------------------------------------------
__global__ __launch_bounds__(512, 4) void attn_main_kernel(
    const ushort_t* __restrict__ Qhi, const ushort_t* __restrict__ Qlo,
    const ushort_t* __restrict__ Khi, const ushort_t* __restrict__ Klo,
    const ushort_t* __restrict__ Vb, const int* __restrict__ cnts,
    ushort_t* __restrict__ Oh, float* __restrict__ mstat,
    float* __restrict__ lstat) {
    const int t = threadIdx.x;
    const int lane = t & 63;
    const int w = t >> 6;
    const int quad = lane >> 4;
    const int col = lane & 15;
    const int qb = blockIdx.x * 32;
    const int half = blockIdx.y;
    const int b = blockIdx.z;

    const int cnt = cnts[b];
    const int nit = (cnt + 127) >> 7;
    const int it0 = half ? (nit + 1) >> 1 : 0;
    const int it1 = half ? nit : (nit + 1) >> 1;

    __shared__ __align__(16) ushort_t P_s[32][136];
    __shared__ float tmax_s[8][32], tsum_s[8][32];
    __shared__ float mrun[32], lrun[32];

    short8 qfh[2][4], qfl[2][4];
    {
        const ushort_t* qhp = Qhi + ((size_t)b * NQ + qb) * DK;
        const ushort_t* qlp = Qlo + ((size_t)b * NQ + qb) * DK;
#pragma unroll
        for (int qt = 0; qt < 2; ++qt)
#pragma unroll
            for (int ks = 0; ks < 4; ++ks) {
                size_t off = (size_t)(qt * 16 + col) * DK + ks * 32 + quad * 8;
                qfh[qt][ks] = *(const short8*)(qhp + off);
                qfl[qt][ks] = *(const short8*)(qlp + off);
            }
    }

    if (t < 32) { mrun[t] = -3.0e38f; lrun[t] = 0.0f; }
    __syncthreads();

    const ushort_t* khp = Khi + ((size_t)b * NM + w * 16 + col) * DK + quad * 8;
    const ushort_t* klp = Klo + ((size_t)b * NM + w * 16 + col) * DK + quad * 8;
    const ushort_t* vp  = Vb + ((size_t)b * DV + w * 64 + col) * NM + quad * 8;

    const f32x4 zero4 = {0.f, 0.f, 0.f, 0.f};
    f32x4 accO[4][2];
#pragma unroll
    for (int vt = 0; vt < 4; ++vt)
#pragma unroll
        for (int qt = 0; qt < 2; ++qt) accO[vt][qt] = zero4;

    for (int it = it0; it < it1; ++it) {
        const int mb = it * 128;

        // ---- QK (split bf16), K frags straight from global ----
        f32x4 accS[2];
        accS[0] = zero4; accS[1] = zero4;
#pragma unroll
        for (int ks = 0; ks < 4; ++ks) {
            short8 ah = *(const short8*)(khp + (size_t)mb * DK + ks * 32);
            short8 al = *(const short8*)(klp + (size_t)mb * DK + ks * 32);
            accS[0] = __builtin_amdgcn_mfma_f32_16x16x32_bf16(ah, qfh[0][ks], accS[0], 0, 0, 0);
            accS[1] = __builtin_amdgcn_mfma_f32_16x16x32_bf16(ah, qfh[1][ks], accS[1], 0, 0, 0);
            accS[0] = __builtin_amdgcn_mfma_f32_16x16x32_bf16(ah, qfl[0][ks], accS[0], 0, 0, 0);
            accS[1] = __builtin_amdgcn_mfma_f32_16x16x32_bf16(ah, qfl[1][ks], accS[1], 0, 0, 0);
            accS[0] = __builtin_amdgcn_mfma_f32_16x16x32_bf16(al, qfh[0][ks], accS[0], 0, 0, 0);
            accS[1] = __builtin_amdgcn_mfma_f32_16x16x32_bf16(al, qfh[1][ks], accS[1], 0, 0, 0);
        }

        // ---- mask(tail) + scale + per-wave column max ----
        const int mrow = mb + w * 16 + quad * 4;
        float s[2][4];
#pragma unroll
        for (int qt = 0; qt < 2; ++qt) {
            float tm = -3.0e38f;
#pragma unroll
            for (int r = 0; r < 4; ++r) {
                s[qt][r] = (mrow + r < cnt) ? accS[qt][r] * 40.0f : -1e9f;
                tm = fmaxf(tm, s[qt][r]);
            }
            tm = fmaxf(tm, __shfl_xor(tm, 16, 64));
            tm = fmaxf(tm, __shfl_xor(tm, 32, 64));
            if (lane < 16) tmax_s[w][qt * 16 + col] = tm;
        }
        __syncthreads();  // sync1

        // ---- softmax, P->LDS, rescale O ----
        float mnew[2], alpha[2];
#pragma unroll
        for (int qt = 0; qt < 2; ++qt) {
            int q = qt * 16 + col;
            float mo = mrun[q];
            float mn = mo;
#pragma unroll
            for (int ww = 0; ww < 8; ++ww) mn = fmaxf(mn, tmax_s[ww][q]);
            mnew[qt] = mn;
            alpha[qt] = __expf(mo - mn);
        }
#pragma unroll
        for (int qt = 0; qt < 2; ++qt) {
            float p0 = __expf(s[qt][0] - mnew[qt]);
            float p1 = __expf(s[qt][1] - mnew[qt]);
            float p2 = __expf(s[qt][2] - mnew[qt]);
            float p3 = __expf(s[qt][3] - mnew[qt]);
            ushort4 pk;
            pk.x = f2bf(p0); pk.y = f2bf(p1); pk.z = f2bf(p2); pk.w = f2bf(p3);
            *(ushort4*)&P_s[qt * 16 + col][w * 16 + quad * 4] = pk;
            float ps = p0 + p1 + p2 + p3;
            ps += __shfl_xor(ps, 16, 64);
            ps += __shfl_xor(ps, 32, 64);
            if (lane < 16) tsum_s[w][qt * 16 + col] = ps;
#pragma unroll
            for (int vt = 0; vt < 4; ++vt)
#pragma unroll
                for (int r = 0; r < 4; ++r) accO[vt][qt][r] *= alpha[qt];
        }
        __syncthreads();  // sync2

        // ---- stats update + PV ----
        if (t < 32) {
            float mo = mrun[t], mn = mo;
#pragma unroll
            for (int ww = 0; ww < 8; ++ww) mn = fmaxf(mn, tmax_s[ww][t]);
            float sm = 0.f;
#pragma unroll
            for (int ww = 0; ww < 8; ++ww) sm += tsum_s[ww][t];
            lrun[t] = lrun[t] * __expf(mo - mn) + sm;
            mrun[t] = mn;
        }
#pragma unroll
        for (int ks = 0; ks < 4; ++ks) {
            short8 b0 = *(const short8*)&P_s[col][ks * 32 + quad * 8];
            short8 b1 = *(const short8*)&P_s[16 + col][ks * 32 + quad * 8];
#pragma unroll
            for (int vt = 0; vt < 4; ++vt) {
                short8 av = *(const short8*)(vp + (size_t)vt * 16 * NM + mb + ks * 32);
                accO[vt][0] = __builtin_amdgcn_mfma_f32_16x16x32_bf16(av, b0, accO[vt][0], 0, 0, 0);
                accO[vt][1] = __builtin_amdgcn_mfma_f32_16x16x32_bf16(av, b1, accO[vt][1], 0, 0, 0);
            }
        }
    }
    __syncthreads();

    // ---- epilogue: unnormalized O' (bf16) + stats ----
    ushort_t* op = Oh + ((size_t)(half * BATCH + b) * DV) * NQ;
#pragma unroll
    for (int qt = 0; qt < 2; ++qt) {
        int q = qb + qt * 16 + col;
#pragma unroll
        for (int vt = 0; vt < 4; ++vt)
#pragma unroll
            for (int r = 0; r < 4; ++r) {
                int dv = w * 64 + vt * 16 + quad * 4 + r;
                op[(size_t)dv * NQ + q] = f2bf(accO[vt][qt][r]);
            }
    }
    if (t < 32) {
        size_t so = (size_t)(half * BATCH + b) * NQ + qb + t;
        mstat[so] = mrun[t];
        lstat[so] = lrun[t];
    }
}

// ---------------------------------------------------------------------------
// combine: merge the two m-halves, normalize, gate, write fp32 output.
// thread handles 8 consecutive q for one dv.
// ---------------------------------------------------------------------------
__global__ __launch_bounds__(256) void combine_kernel(
    const ushort_t* __restrict__ Oh, const float* __restrict__ mstat,
    const float* __restrict__ lstat, const int* __restrict__ cnts,
    const int* __restrict__ qflags, const int* __restrict__ qmask,
    float* __restrict__ out) {
    const size_t idx = (size_t)blockIdx.x * 256 + threadIdx.x;
    const int q0 = (int)((idx % (NQ / 8)) * 8);
    const int dv = (int)((idx / (NQ / 8)) % DV);
    const int b = (int)(idx / ((size_t)(NQ / 8) * DV));

    const size_t HS = (size_t)BATCH * DV * NQ;   // O' half stride
    const size_t SB = (size_t)BATCH * NQ;        // stats half stride

    const size_t so = (size_t)b * NQ + q0;
    float m1[8], l1[8], m2[8], l2[8];
    *(float4*)&m1[0] = *(const float4*)(mstat + so);
    *(float4*)&m1[4] = *(const float4*)(mstat + so + 4);
    *(float4*)&l1[0] = *(const float4*)(lstat + so);
    *(float4*)&l1[4] = *(const float4*)(lstat + so + 4);
    *(float4*)&m2[0] = *(const float4*)(mstat + SB + so);
    *(float4*)&m2[4] = *(const float4*)(mstat + SB + so + 4);
    *(float4*)&l2[0] = *(const float4*)(lstat + SB + so);
    *(float4*)&l2[4] = *(const float4*)(lstat + SB + so + 4);

    const size_t oo = ((size_t)b * DV + dv) * NQ + q0;
    ushort4 o1a = *(const ushort4*)(Oh + oo);
    ushort4 o1b = *(const ushort4*)(Oh + oo + 4);
    ushort4 o2a = *(const ushort4*)(Oh + HS + oo);
    ushort4 o2b = *(const ushort4*)(Oh + HS + oo + 4);
    ushort_t o1[8] = {o1a.x, o1a.y, o1a.z, o1a.w, o1b.x, o1b.y, o1b.z, o1b.w};
    ushort_t o2[8] = {o2a.x, o2a.y, o2a.z, o2a.w, o2b.x, o2b.y, o2b.z, o2b.w};

    const int gate = (qflags[b] != 0) && (cnts[b] > 0);
    int qm[8];
    *(int4*)&qm[0] = *(const int4*)(qmask + b * NQ + q0);
    *(int4*)&qm[4] = *(const int4*)(qmask + b * NQ + q0 + 4);

    float res[8];
#pragma unroll
    for (int j = 0; j < 8; ++j) {
        float M = fmaxf(m1[j], m2[j]);
        float w1 = __expf(m1[j] - M);
        float w2 = __expf(m2[j] - M);
        float l = w1 * l1[j] + w2 * l2[j];
        float osum = w1 * bf2f(o1[j]) + w2 * bf2f(o2[j]);
        bool valid = gate && (qm[j] != 0) && (l > 0.f);
        res[j] = valid ? osum / l : 0.0f;
    }
    float4 r0 = {res[0], res[1], res[2], res[3]};
    float4 r1 = {res[4], res[5], res[6], res[7]};
    *(float4*)(out + oo) = r0;
    *(float4*)(out + oo + 4) = r1;
}

// ---------------------------------------------------------------------------
extern "C" void kernel_launch(void* const* d_in, const int* in_sizes, int n_in,
                              void* d_out, int out_size, void* d_ws, size_t ws_size,
                              hipStream_t stream) {
    const float* qkey  = (const float*)d_in[0];
    // d_in[1] (qval) unused by the reference
    const int*   qmask = (const int*)d_in[2];
    const float* mkey  = (const float*)d_in[3];
    const float* mval  = (const float*)d_in[4];
    const int*   mmask = (const int*)d_in[5];
    float* out = (float*)d_out;

    char* ws = (char*)d_ws;
    size_t off = 0;
    const size_t QS = (size_t)BATCH * NQ * DK * 2;   // 2 MB
    const size_t KS = (size_t)BATCH * NM * DK * 2;   // 4 MB
    const size_t VS = (size_t)BATCH * DV * NM * 2;   // 16 MB
    const size_t OS = (size_t)BATCH * DV * NQ * 2;   // 8 MB per half
    ushort_t* Qhi = (ushort_t*)(ws + off); off += QS;
    ushort_t* Qlo = (ushort_t*)(ws + off); off += QS;
    ushort_t* Khi = (ushort_t*)(ws + off); off += KS;
    ushort_t* Klo = (ushort_t*)(ws + off); off += KS;
    ushort_t* Vc  = (ushort_t*)(ws + off); off += VS;
    ushort_t* Oh  = (ushort_t*)(ws + off); off += 2 * OS;
    float* mstat  = (float*)(ws + off); off += 2 * (size_t)BATCH * NQ * 4;
    float* lstat  = (float*)(ws + off); off += 2 * (size_t)BATCH * NQ * 4;
    int* cidx     = (int*)(ws + off); off += (size_t)BATCH * NM * 4;
    int* cpos     = (int*)(ws + off); off += (size_t)BATCH * NM * 4;
    int* cnts     = (int*)(ws + off); off += 64;
    int* qflags   = (int*)(ws + off); off += 64;

    scan_kernel<<<BATCH, 256, 0, stream>>>(qmask, mmask, cidx, cpos, cnts, qflags);

    dim3 gq(NQ / 32, DK / 32, BATCH);
    prep_q_kernel<<<gq, 256, 0, stream>>>(qkey, Qhi, Qlo);
    dim3 gk(NM / 32, DK / 32, BATCH);
    prep_k_kernel<<<gk, 256, 0, stream>>>(mkey, mmask, cpos, Khi, Klo);

    const int vblocks = (int)(((size_t)BATCH * DV * (NM / 4)) / 256);
    prep_v_kernel<<<vblocks, 256, 0, stream>>>(mval, cidx, cnts, Vc);

    dim3 gm(NQ / 32, 2, BATCH);
    attn_main_kernel<<<gm, 512, 0, stream>>>(Qhi, Qlo, Khi, Klo, Vc, cnts,
                                             Oh, mstat, lstat);

    const int cblocks = (int)(((size_t)BATCH * DV * (NQ / 8)) / 256);
    combine_kernel<<<cblocks, 256, 0, stream>>>(Oh, mstat, lstat, cnts,
                                                qflags, qmask, out);
}

// Round 5
// 364.237 us; speedup vs baseline: 206.2321x; 1.0992x over previous
//
#include <hip/hip_runtime.h>

#define NQ 4096
#define NM 8192
#define DK 128
#define DV 512
#define BATCH 2

typedef __attribute__((ext_vector_type(8))) short short8;
typedef __attribute__((ext_vector_type(4))) float f32x4;
typedef unsigned short ushort_t;

static __device__ __forceinline__ unsigned short f2bf(float x) {
    union { float f; unsigned int u; } c; c.f = x;
    unsigned int u = c.u;
    return (unsigned short)((u + 0x7FFFu + ((u >> 16) & 1u)) >> 16);
}
static __device__ __forceinline__ float bf2f(unsigned short h) {
    union { unsigned int u; float f; } c; c.u = ((unsigned int)h) << 16;
    return c.f;
}

// ---------------------------------------------------------------------------
// scan: per-batch compaction of mmask (1024 threads, shfl wave scans).
//   cidx[b][i'] = original m of i'-th valid row; cpos[b][m] = exclusive prefix
//   cnts[b] = count; qflags[b] = any(qmask[b])
// ---------------------------------------------------------------------------
__global__ __launch_bounds__(1024) void scan_kernel(
    const int* __restrict__ qmask, const int* __restrict__ mmask,
    int* __restrict__ cidx, int* __restrict__ cpos,
    int* __restrict__ cnts, int* __restrict__ qflags) {
    const int b = blockIdx.x;
    const int t = threadIdx.x;
    const int lane = t & 63;
    const int w = t >> 6;   // 16 waves
    __shared__ int wsum[16];
    __shared__ int qsh;

    const int* mp = mmask + b * NM;
    const int base = t * 8;
    int val[8];
#pragma unroll
    for (int i = 0; i < 8; ++i) val[i] = (mp[base + i] != 0);
    int c0 = 0;
#pragma unroll
    for (int i = 0; i < 8; ++i) c0 += val[i];

    // inclusive scan within wave
    int c = c0;
#pragma unroll
    for (int off = 1; off < 64; off <<= 1) {
        int n = __shfl_up(c, off, 64);
        if (lane >= off) c += n;
    }
    if (lane == 63) wsum[w] = c;
    if (t == 0) qsh = 0;
    __syncthreads();
    if (t == 0) {
        int s = 0;
#pragma unroll
        for (int i = 0; i < 16; ++i) { s += wsum[i]; wsum[i] = s; }
    }
    __syncthreads();
    const int wbase = (w == 0) ? 0 : wsum[w - 1];
    int run = wbase + (c - c0);   // exclusive prefix for this thread
#pragma unroll
    for (int i = 0; i < 8; ++i) {
        int m = base + i;
        cpos[b * NM + m] = run;
        if (val[i]) { cidx[b * NM + run] = m; ++run; }
    }

    int qa = 0;
    for (int i = t; i < NQ; i += 1024) qa |= (qmask[b * NQ + i] != 0);
    if (qa) atomicOr(&qsh, 1);
    __syncthreads();
    if (t == 0) { cnts[b] = wsum[15]; qflags[b] = qsh; }
}

// ---------------------------------------------------------------------------
// prep Q: transpose [B][DK][NQ] fp32 -> [B][q][DK] bf16 hi/lo
// ---------------------------------------------------------------------------
__global__ __launch_bounds__(256) void prep_q_kernel(
    const float* __restrict__ src, ushort_t* __restrict__ hi,
    ushort_t* __restrict__ lo) {
    const int b = blockIdx.z;
    const int d0 = blockIdx.y * 32;
    const int n0 = blockIdx.x * 32;
    __shared__ float t32[32][33];
    for (int l = threadIdx.x; l < 1024; l += 256) {
        int r = l >> 5, c = l & 31;
        t32[r][c] = src[((size_t)b * DK + d0 + r) * NQ + n0 + c];
    }
    __syncthreads();
    for (int l = threadIdx.x; l < 1024; l += 256) {
        int r = l >> 5, c = l & 31;
        float f = t32[c][r];
        unsigned short h = f2bf(f);
        unsigned short lw = f2bf(f - bf2f(h));
        size_t off = ((size_t)b * NQ + n0 + r) * DK + d0 + c;
        hi[off] = h;
        lo[off] = lw;
    }
}

// ---------------------------------------------------------------------------
// prep K: transpose + compacting gather [B][DK][NM] -> [B][m'][DK] hi/lo
// ---------------------------------------------------------------------------
__global__ __launch_bounds__(256) void prep_k_kernel(
    const float* __restrict__ src, const int* __restrict__ mmask,
    const int* __restrict__ cpos,
    ushort_t* __restrict__ hi, ushort_t* __restrict__ lo) {
    const int b = blockIdx.z;
    const int d0 = blockIdx.y * 32;
    const int n0 = blockIdx.x * 32;
    __shared__ float t32[32][33];
    for (int l = threadIdx.x; l < 1024; l += 256) {
        int r = l >> 5, c = l & 31;
        t32[r][c] = src[((size_t)b * DK + d0 + r) * NM + n0 + c];
    }
    __syncthreads();
    for (int l = threadIdx.x; l < 1024; l += 256) {
        int r = l >> 5, c = l & 31;
        int m = n0 + r;
        if (mmask[b * NM + m] != 0) {
            int pos = cpos[b * NM + m];
            float f = t32[c][r];
            unsigned short h = f2bf(f);
            unsigned short lw = f2bf(f - bf2f(h));
            size_t off = ((size_t)b * NM + pos) * DK + d0 + c;
            hi[off] = h;
            lo[off] = lw;
        }
    }
}

// ---------------------------------------------------------------------------
// prep V: compacting gather + convert [B][DV][NM] fp32 -> [B][DV][m'] bf16
// ---------------------------------------------------------------------------
__global__ __launch_bounds__(256) void prep_v_kernel(
    const float* __restrict__ src, const int* __restrict__ cidx,
    const int* __restrict__ cnts, ushort_t* __restrict__ dst) {
    const size_t idx = (size_t)blockIdx.x * 256 + threadIdx.x;
    const int mi4 = (int)((idx % (NM / 4)) * 4);
    const int dv = (int)((idx / (NM / 4)) % DV);
    const int b = (int)(idx / ((size_t)(NM / 4) * DV));
    const int cnt = cnts[b];

    int4 ci = *(const int4*)(cidx + b * NM + mi4);
    int i0 = (mi4 + 0 < cnt) ? ci.x : 0;
    int i1 = (mi4 + 1 < cnt) ? ci.y : 0;
    int i2 = (mi4 + 2 < cnt) ? ci.z : 0;
    int i3 = (mi4 + 3 < cnt) ? ci.w : 0;
    const float* row = src + ((size_t)b * DV + dv) * NM;
    ushort4 o;
    o.x = (mi4 + 0 < cnt) ? f2bf(row[i0]) : (ushort_t)0;
    o.y = (mi4 + 1 < cnt) ? f2bf(row[i1]) : (ushort_t)0;
    o.z = (mi4 + 2 < cnt) ? f2bf(row[i2]) : (ushort_t)0;
    o.w = (mi4 + 3 < cnt) ? f2bf(row[i3]) : (ushort_t)0;
    *(ushort4*)(dst + ((size_t)b * DV + dv) * NM + mi4) = o;
}

// ---------------------------------------------------------------------------
// main: flash attention over compacted rows. q-tile 64, m-tile 128,
// 1024 threads (16 waves), 2-way m-split, XCD-swizzled block decode.
// QK: wave (mw = w>>1, qh = w&1): S rows mw*16.., q-half qh*32..
// PV: wave w: dv rows [w*32, w*32+32), all 64 q.
// ---------------------------------------------------------------------------
__global__ __launch_bounds__(1024, 4) void attn_main_kernel(
    const ushort_t* __restrict__ Qhi, const ushort_t* __restrict__ Qlo,
    const ushort_t* __restrict__ Khi, const ushort_t* __restrict__ Klo,
    const ushort_t* __restrict__ Vb, const int* __restrict__ cnts,
    ushort_t* __restrict__ Oh, float* __restrict__ mstat,
    float* __restrict__ lstat) {
    const int t = threadIdx.x;
    const int lane = t & 63;
    const int w = t >> 6;          // 0..15
    const int quad = lane >> 4;
    const int col = lane & 15;
    // XCD-aware decode: combo c -> XCDs {c, c+4}; each XCD serves one (b,half)
    const int bid = blockIdx.x;
    const int cmb = bid & 3;
    const int half = cmb & 1;
    const int b = cmb >> 1;
    const int qb = (bid >> 2) * 64;

    const int mw = w >> 1;         // m-group 0..7
    const int qh = w & 1;          // q-half 0..1

    const int cnt = cnts[b];
    const int nit = (cnt + 127) >> 7;
    const int it0 = half ? (nit + 1) >> 1 : 0;
    const int it1 = half ? nit : (nit + 1) >> 1;

    __shared__ __align__(16) ushort_t P_s[64][136];
    __shared__ float tmax_s[2][8][64];   // parity-buffered (race fix)
    __shared__ float tsum_s[8][64];
    __shared__ float mrun[64], lrun[64];

    // resident Q frags for this wave's q-half
    short8 qfh[2][4], qfl[2][4];
    {
        const ushort_t* qhp = Qhi + ((size_t)b * NQ + qb + qh * 32) * DK;
        const ushort_t* qlp = Qlo + ((size_t)b * NQ + qb + qh * 32) * DK;
#pragma unroll
        for (int qt = 0; qt < 2; ++qt)
#pragma unroll
            for (int ks = 0; ks < 4; ++ks) {
                size_t off = (size_t)(qt * 16 + col) * DK + ks * 32 + quad * 8;
                qfh[qt][ks] = *(const short8*)(qhp + off);
                qfl[qt][ks] = *(const short8*)(qlp + off);
            }
    }

    if (t < 64) { mrun[t] = -3.0e38f; lrun[t] = 0.0f; }
    __syncthreads();

    const ushort_t* khp = Khi + ((size_t)b * NM + mw * 16 + col) * DK + quad * 8;
    const ushort_t* klp = Klo + ((size_t)b * NM + mw * 16 + col) * DK + quad * 8;
    const ushort_t* vp  = Vb + ((size_t)b * DV + w * 32 + col) * NM + quad * 8;

    const f32x4 zero4 = {0.f, 0.f, 0.f, 0.f};
    f32x4 accO[2][4];   // [vt][qf]
#pragma unroll
    for (int vt = 0; vt < 2; ++vt)
#pragma unroll
        for (int qf = 0; qf < 4; ++qf) accO[vt][qf] = zero4;

    for (int it = it0; it < it1; ++it) {
        const int mb = it * 128;
        const int par = it & 1;

        // ---- phase A: QK (split bf16), K straight from global ----
        f32x4 accS[2];
        accS[0] = zero4; accS[1] = zero4;
#pragma unroll
        for (int ks = 0; ks < 4; ++ks) {
            short8 ah = *(const short8*)(khp + (size_t)mb * DK + ks * 32);
            short8 al = *(const short8*)(klp + (size_t)mb * DK + ks * 32);
            accS[0] = __builtin_amdgcn_mfma_f32_16x16x32_bf16(ah, qfh[0][ks], accS[0], 0, 0, 0);
            accS[1] = __builtin_amdgcn_mfma_f32_16x16x32_bf16(ah, qfh[1][ks], accS[1], 0, 0, 0);
            accS[0] = __builtin_amdgcn_mfma_f32_16x16x32_bf16(ah, qfl[0][ks], accS[0], 0, 0, 0);
            accS[1] = __builtin_amdgcn_mfma_f32_16x16x32_bf16(ah, qfl[1][ks], accS[1], 0, 0, 0);
            accS[0] = __builtin_amdgcn_mfma_f32_16x16x32_bf16(al, qfh[0][ks], accS[0], 0, 0, 0);
            accS[1] = __builtin_amdgcn_mfma_f32_16x16x32_bf16(al, qfh[1][ks], accS[1], 0, 0, 0);
        }

        // ---- phase B: mask(tail) + scale + per-wave column max ----
        const int mrow = mb + mw * 16 + quad * 4;
        float s[2][4];
#pragma unroll
        for (int qt = 0; qt < 2; ++qt) {
            float tm = -3.0e38f;
#pragma unroll
            for (int r = 0; r < 4; ++r) {
                s[qt][r] = (mrow + r < cnt) ? accS[qt][r] * 40.0f : -1e9f;
                tm = fmaxf(tm, s[qt][r]);
            }
            tm = fmaxf(tm, __shfl_xor(tm, 16, 64));
            tm = fmaxf(tm, __shfl_xor(tm, 32, 64));
            if (lane < 16) tmax_s[par][mw][qh * 32 + qt * 16 + col] = tm;
        }
        __syncthreads();  // sync1: tmax published; prev-iter P/tsum reads done

        // ---- phase C: softmax, P->LDS, rescale O ----
        float mnewF[4], alphaF[4];
#pragma unroll
        for (int qf = 0; qf < 4; ++qf) {
            int q = qf * 16 + col;
            float mo = mrun[q];
            float mn = mo;
#pragma unroll
            for (int ww = 0; ww < 8; ++ww) mn = fmaxf(mn, tmax_s[par][ww][q]);
            mnewF[qf] = mn;
            alphaF[qf] = __expf(mo - mn);
        }
#pragma unroll
        for (int qt = 0; qt < 2; ++qt) {
            const float mn = mnewF[qh * 2 + qt];
            float p0 = __expf(s[qt][0] - mn);
            float p1 = __expf(s[qt][1] - mn);
            float p2 = __expf(s[qt][2] - mn);
            float p3 = __expf(s[qt][3] - mn);
            ushort4 pk;
            pk.x = f2bf(p0); pk.y = f2bf(p1); pk.z = f2bf(p2); pk.w = f2bf(p3);
            *(ushort4*)&P_s[qh * 32 + qt * 16 + col][mw * 16 + quad * 4] = pk;
            float ps = p0 + p1 + p2 + p3;
            ps += __shfl_xor(ps, 16, 64);
            ps += __shfl_xor(ps, 32, 64);
            if (lane < 16) tsum_s[mw][qh * 32 + qt * 16 + col] = ps;
        }
#pragma unroll
        for (int vt = 0; vt < 2; ++vt)
#pragma unroll
            for (int qf = 0; qf < 4; ++qf)
#pragma unroll
                for (int r = 0; r < 4; ++r) accO[vt][qf][r] *= alphaF[qf];
        __syncthreads();  // sync2: P + tsum published

        // ---- phase D: stats update + PV (V straight from global) ----
        if (t < 64) {
            float mo = mrun[t], mn = mo;
#pragma unroll
            for (int ww = 0; ww < 8; ++ww) mn = fmaxf(mn, tmax_s[par][ww][t]);
            float sm = 0.f;
#pragma unroll
            for (int ww = 0; ww < 8; ++ww) sm += tsum_s[ww][t];
            lrun[t] = lrun[t] * __expf(mo - mn) + sm;
            mrun[t] = mn;
        }
#pragma unroll
        for (int ks = 0; ks < 4; ++ks) {
            short8 bp[4];
#pragma unroll
            for (int qf = 0; qf < 4; ++qf)
                bp[qf] = *(const short8*)&P_s[qf * 16 + col][ks * 32 + quad * 8];
#pragma unroll
            for (int vt = 0; vt < 2; ++vt) {
                short8 av = *(const short8*)(vp + (size_t)vt * 16 * NM + mb + ks * 32);
#pragma unroll
                for (int qf = 0; qf < 4; ++qf)
                    accO[vt][qf] = __builtin_amdgcn_mfma_f32_16x16x32_bf16(av, bp[qf], accO[vt][qf], 0, 0, 0);
            }
        }
        // next-iter sync1 protects P_s/tsum; tmax is parity-buffered
    }
    __syncthreads();

    // ---- epilogue: unnormalized O' (bf16) + stats ----
    ushort_t* op = Oh + ((size_t)(half * BATCH + b) * DV) * NQ;
#pragma unroll
    for (int qf = 0; qf < 4; ++qf) {
        int q = qb + qf * 16 + col;
#pragma unroll
        for (int vt = 0; vt < 2; ++vt)
#pragma unroll
            for (int r = 0; r < 4; ++r) {
                int dv = w * 32 + vt * 16 + quad * 4 + r;
                op[(size_t)dv * NQ + q] = f2bf(accO[vt][qf][r]);
            }
    }
    if (t < 64) {
        size_t so = (size_t)(half * BATCH + b) * NQ + qb + t;
        mstat[so] = mrun[t];
        lstat[so] = lrun[t];
    }
}

// ---------------------------------------------------------------------------
// combine: merge m-halves, normalize, gate, write fp32 output.
// ---------------------------------------------------------------------------
__global__ __launch_bounds__(256) void combine_kernel(
    const ushort_t* __restrict__ Oh, const float* __restrict__ mstat,
    const float* __restrict__ lstat, const int* __restrict__ cnts,
    const int* __restrict__ qflags, const int* __restrict__ qmask,
    float* __restrict__ out) {
    const size_t idx = (size_t)blockIdx.x * 256 + threadIdx.x;
    const int q0 = (int)((idx % (NQ / 8)) * 8);
    const int dv = (int)((idx / (NQ / 8)) % DV);
    const int b = (int)(idx / ((size_t)(NQ / 8) * DV));

    const size_t HS = (size_t)BATCH * DV * NQ;
    const size_t SB = (size_t)BATCH * NQ;

    const size_t so = (size_t)b * NQ + q0;
    float m1[8], l1[8], m2[8], l2[8];
    *(float4*)&m1[0] = *(const float4*)(mstat + so);
    *(float4*)&m1[4] = *(const float4*)(mstat + so + 4);
    *(float4*)&l1[0] = *(const float4*)(lstat + so);
    *(float4*)&l1[4] = *(const float4*)(lstat + so + 4);
    *(float4*)&m2[0] = *(const float4*)(mstat + SB + so);
    *(float4*)&m2[4] = *(const float4*)(mstat + SB + so + 4);
    *(float4*)&l2[0] = *(const float4*)(lstat + SB + so);
    *(float4*)&l2[4] = *(const float4*)(lstat + SB + so + 4);

    const size_t oo = ((size_t)b * DV + dv) * NQ + q0;
    ushort4 o1a = *(const ushort4*)(Oh + oo);
    ushort4 o1b = *(const ushort4*)(Oh + oo + 4);
    ushort4 o2a = *(const ushort4*)(Oh + HS + oo);
    ushort4 o2b = *(const ushort4*)(Oh + HS + oo + 4);
    ushort_t o1[8] = {o1a.x, o1a.y, o1a.z, o1a.w, o1b.x, o1b.y, o1b.z, o1b.w};
    ushort_t o2[8] = {o2a.x, o2a.y, o2a.z, o2a.w, o2b.x, o2b.y, o2b.z, o2b.w};

    const int gate = (qflags[b] != 0) && (cnts[b] > 0);
    int qm[8];
    *(int4*)&qm[0] = *(const int4*)(qmask + b * NQ + q0);
    *(int4*)&qm[4] = *(const int4*)(qmask + b * NQ + q0 + 4);

    float res[8];
#pragma unroll
    for (int j = 0; j < 8; ++j) {
        float M = fmaxf(m1[j], m2[j]);
        float w1 = __expf(m1[j] - M);
        float w2 = __expf(m2[j] - M);
        float l = w1 * l1[j] + w2 * l2[j];
        float osum = w1 * bf2f(o1[j]) + w2 * bf2f(o2[j]);
        bool valid = gate && (qm[j] != 0) && (l > 0.f);
        res[j] = valid ? osum / l : 0.0f;
    }
    float4 r0 = {res[0], res[1], res[2], res[3]};
    float4 r1 = {res[4], res[5], res[6], res[7]};
    *(float4*)(out + oo) = r0;
    *(float4*)(out + oo + 4) = r1;
}

// ---------------------------------------------------------------------------
extern "C" void kernel_launch(void* const* d_in, const int* in_sizes, int n_in,
                              void* d_out, int out_size, void* d_ws, size_t ws_size,
                              hipStream_t stream) {
    const float* qkey  = (const float*)d_in[0];
    // d_in[1] (qval) unused by the reference
    const int*   qmask = (const int*)d_in[2];
    const float* mkey  = (const float*)d_in[3];
    const float* mval  = (const float*)d_in[4];
    const int*   mmask = (const int*)d_in[5];
    float* out = (float*)d_out;

    char* ws = (char*)d_ws;
    size_t off = 0;
    const size_t QS = (size_t)BATCH * NQ * DK * 2;
    const size_t KS = (size_t)BATCH * NM * DK * 2;
    const size_t VS = (size_t)BATCH * DV * NM * 2;
    const size_t OS = (size_t)BATCH * DV * NQ * 2;
    ushort_t* Qhi = (ushort_t*)(ws + off); off += QS;
    ushort_t* Qlo = (ushort_t*)(ws + off); off += QS;
    ushort_t* Khi = (ushort_t*)(ws + off); off += KS;
    ushort_t* Klo = (ushort_t*)(ws + off); off += KS;
    ushort_t* Vc  = (ushort_t*)(ws + off); off += VS;
    ushort_t* Oh  = (ushort_t*)(ws + off); off += 2 * OS;
    float* mstat  = (float*)(ws + off); off += 2 * (size_t)BATCH * NQ * 4;
    float* lstat  = (float*)(ws + off); off += 2 * (size_t)BATCH * NQ * 4;
    int* cidx     = (int*)(ws + off); off += (size_t)BATCH * NM * 4;
    int* cpos     = (int*)(ws + off); off += (size_t)BATCH * NM * 4;
    int* cnts     = (int*)(ws + off); off += 64;
    int* qflags   = (int*)(ws + off); off += 64;

    scan_kernel<<<BATCH, 1024, 0, stream>>>(qmask, mmask, cidx, cpos, cnts, qflags);

    dim3 gq(NQ / 32, DK / 32, BATCH);
    prep_q_kernel<<<gq, 256, 0, stream>>>(qkey, Qhi, Qlo);
    dim3 gk(NM / 32, DK / 32, BATCH);
    prep_k_kernel<<<gk, 256, 0, stream>>>(mkey, mmask, cpos, Khi, Klo);

    const int vblocks = (int)(((size_t)BATCH * DV * (NM / 4)) / 256);
    prep_v_kernel<<<vblocks, 256, 0, stream>>>(mval, cidx, cnts, Vc);

    // 256 blocks linear; in-kernel decode gives each XCD one (b,half) combo
    attn_main_kernel<<<(NQ / 64) * 4, 1024, 0, stream>>>(
        Qhi, Qlo, Khi, Klo, Vc, cnts, Oh, mstat, lstat);

    const int cblocks = (int)(((size_t)BATCH * DV * (NQ / 8)) / 256);
    combine_kernel<<<cblocks, 256, 0, stream>>>(Oh, mstat, lstat, cnts,
                                                qflags, qmask, out);
}